// Round 10
// baseline (75.599 us; speedup 1.0000x reference)
//
#include <hip/hip_runtime.h>

#define L_   4096
#define LIM0 4093   // L-3 (tp positions)
#define LIM1 4092   // L-4 (pp positions)

typedef short s16x8 __attribute__((ext_vector_type(8)));
typedef float f32x4 __attribute__((ext_vector_type(4)));

__device__ __forceinline__ unsigned int cvt_pk_bf16(float lo, float hi) {
    unsigned int r;
    asm("v_cvt_pk_bf16_f32 %0, %1, %2" : "=v"(r) : "v"(lo), "v"(hi));
    return r;
}

struct F3 { float x, y, z; };
__device__ __forceinline__ F3 ld3(const float* p) { return F3{p[0], p[1], p[2]}; }
__device__ __forceinline__ F3 sub3(F3 a, F3 b) { return F3{a.x-b.x, a.y-b.y, a.z-b.z}; }
__device__ __forceinline__ F3 cross3(F3 a, F3 b) {
    return F3{a.y*b.z - a.z*b.y, a.z*b.x - a.x*b.z, a.x*b.y - a.y*b.x};
}
__device__ __forceinline__ float dot3(F3 a, F3 b) { return a.x*b.x + a.y*b.y + a.z*b.z; }

__device__ __forceinline__ void torsion(F3 a, F3 b, F3 c, F3 d, float& sn, float& cs) {
    F3 v1 = sub3(b, a), v2 = sub3(c, b), v3 = sub3(d, c);
    F3 n1 = cross3(v1, v2), n2 = cross3(v2, v3);
    float x = dot3(n1, n2);
    F3 m = cross3(n1, n2);
    float bn = sqrtf(dot3(v2, v2)) + 1e-8f;
    float y = dot3(m, v2) / bn;
    float inv = rsqrtf(x*x + y*y + 1e-30f);
    sn = y * inv; cs = x * inv;
}

#define MFMA16 __builtin_amdgcn_mfma_f32_16x16x32_bf16

// ---- pre-kernel: features (bx<16) + weight-fragment/emb packing (bx==16, y==0) ----
// featG[b*L+p] = {pk(cos_theta, 1.0), pk(sin_phi, cos_phi)}
// wfragG[F], F = (((mode*4+w)*2+mt)*7+kkL)*64 + lane: 8 packed bf16 weight values for
//   hc = w*32+mt*16+ln, k-slots kkL (0-2: W1 cols kk*32+g*8+j permuted+bias; 3-6: W2).
__global__ __launch_bounds__(256) void ss_pre(
    const float* __restrict__ R, uint2* __restrict__ featG,
    const float* __restrict__ emb, uint4* __restrict__ embbfG,
    const float* __restrict__ tpW1, const float* __restrict__ tpb1,
    const float* __restrict__ tpW2,
    const float* __restrict__ ppW1, const float* __restrict__ ppb1,
    const float* __restrict__ ppW2,
    uint4* __restrict__ wfragG) {
    const int t = threadIdx.x;
    if (blockIdx.x == 16) {
        if (blockIdx.y != 0) return;
        if (t < 40) {
            const float* ep = emb + (t >> 1) * 16 + (t & 1) * 8;
            embbfG[t] = make_uint4(cvt_pk_bf16(ep[0], ep[1]), cvt_pk_bf16(ep[2], ep[3]),
                                   cvt_pk_bf16(ep[4], ep[5]), cvt_pk_bf16(ep[6], ep[7]));
        }
        for (int F = t; F < 7168; F += 256) {
            int l = F & 63, q = F >> 6;
            int kkL = q % 7; q /= 7;
            int mt = q & 1; q >>= 1;
            int w = q & 3, mode = q >> 2;
            int g = l >> 4, ln = l & 15;
            int hc = w*32 + mt*16 + ln;
            const float* W1  = mode ? ppW1 : tpW1;
            const float* Bi1 = mode ? ppb1 : tpb1;
            const float* W2  = mode ? ppW2 : tpW2;
            float v[8];
            #pragma unroll
            for (int j = 0; j < 8; j++) {
                if (kkL < 3) {
                    int c = kkL*32 + g*8 + j;
                    int kp;
                    if (mode) kp = (c < 64) ? c + 4 : ((c < 68) ? c - 64 : ((c == 68) ? -2 : -1));
                    else      kp = (c < 64) ? c + 3 : ((c == 64) ? 0 : ((c == 65) ? -2 :
                                   ((c == 66) ? 1 : ((c == 67) ? 2 : -1))));
                    v[j] = (kp == -1) ? 0.f : ((kp == -2) ? Bi1[hc] : W1[kp*128 + hc]);
                } else {
                    v[j] = W2[((kkL - 3)*32 + g*8 + j)*128 + hc];
                }
            }
            wfragG[F] = make_uint4(cvt_pk_bf16(v[0], v[1]), cvt_pk_bf16(v[2], v[3]),
                                   cvt_pk_bf16(v[4], v[5]), cvt_pk_bf16(v[6], v[7]));
        }
        return;
    }
    const int p = blockIdx.x * 256 + t;
    const int b = blockIdx.y;
    if (p >= LIM0) return;
    const float* Rp = R + ((size_t)(b * L_ + p)) * 3;
    F3 p0 = ld3(Rp), p1 = ld3(Rp + 3), p2 = ld3(Rp + 6), p3 = ld3(Rp + 9);
    F3 u1 = sub3(p0, p1), u2 = sub3(p2, p1);
    F3 cr = cross3(u1, u2);
    float d = dot3(u1, u2);
    float ct = d * rsqrtf(d * d + dot3(cr, cr) + 1e-30f);
    float sp, cp; torsion(p0, p1, p2, p3, sp, cp);
    featG[(size_t)b * L_ + p] = make_uint2(cvt_pk_bf16(ct, 1.0f), cvt_pk_bf16(sp, cp));
}

// ---- main: M=128 tile, no X staging; B-frags from VMEM gathers; H1 LDS round-trip only ----
__global__ __launch_bounds__(256) void ss_mlp(
    const int* __restrict__ seq, const uint2* __restrict__ featG,
    const uint4* __restrict__ embbfG, const uint4* __restrict__ wfragG,
    const float* __restrict__ tpb2, const float* __restrict__ ppb2,
    float* __restrict__ wsp) {

    __shared__ __align__(16) unsigned short H1s[128*128];  // [pos][hidden], XOR-swizzled

    const int b = blockIdx.y, mode = blockIdx.z, bx = blockIdx.x;
    const int lim = mode ? LIM1 : LIM0;
    const float* Bi2 = mode ? ppb2 : tpb2;

    const int t = threadIdx.x;
    const int w = t >> 6, l = t & 63, g = l >> 4, ln = l & 15;
    const int lw = ln & 7, g2 = g >> 1, gh = g & 1;
    const size_t bL = (size_t)b * L_;
    const int base = bx * 512;

    // prologue: 14 coalesced fragment loads + bias2
    s16x8 fr[2][7];
    {
        const uint4* wf = wfragG + (size_t)(mode*4 + w) * (2*7*64);
        #pragma unroll
        for (int mt = 0; mt < 2; mt++)
            #pragma unroll
            for (int kkL = 0; kkL < 7; kkL++)
                fr[mt][kkL] = *(const s16x8*)(wf + (mt*7 + kkL)*64 + l);
    }
    float bb2[2][4];
    #pragma unroll
    for (int mt = 0; mt < 2; mt++)
        #pragma unroll
        for (int i = 0; i < 4; i++)
            bb2[mt][i] = Bi2[w*32 + mt*16 + g*4 + i];

    float s[2][4] = {{0.f,0.f,0.f,0.f},{0.f,0.f,0.f,0.f}};

    for (int it = 0; it < 4; it++) {
        const int pos0 = base + it*128;

        // residue indices for all 8 sub-tiles (L1/L2-hot)
        int aa[8][2];
        #pragma unroll
        for (int pt = 0; pt < 8; pt++)
            #pragma unroll
            for (int e = 0; e < 2; e++)
                aa[pt][e] = seq[bL + min(pos0 + pt*16 + ln + e*2 + g2, L_ - 1)];

        // ---- GEMM1: D1 = W1^T·X^T, B-frags gathered from embbfG (VMEM) + featG ----
        #pragma unroll
        for (int pt = 0; pt < 8; pt++) {
            const int row = pt*16 + ln;
            const int pos = pos0 + row;
            s16x8 b0 = *(const s16x8*)(embbfG + aa[pt][0]*2 + gh);
            s16x8 b1 = *(const s16x8*)(embbfG + aa[pt][1]*2 + gh);
            uint2 f0 = make_uint2(0u, 0u), f1 = make_uint2(0u, 0u);
            if (g == 0) {
                const int pc = min(pos, lim - 1);
                f0 = featG[bL + pc];
                if (mode) f1 = featG[bL + pc + 1];
            }
            union { unsigned int u[4]; s16x8 v; } fb;
            if (mode) {
                fb.u[0] = f0.y; fb.u[1] = f1.y;
                fb.u[2] = (g == 0) ? 0x00003F80u : 0u; fb.u[3] = 0u;
            } else {
                fb.u[0] = f0.x; fb.u[1] = f0.y; fb.u[2] = 0u; fb.u[3] = 0u;
            }
            f32x4 c0 = {0.f,0.f,0.f,0.f}, c1 = {0.f,0.f,0.f,0.f};
            c0 = MFMA16(fr[0][0], b0,   c0, 0, 0, 0);
            c1 = MFMA16(fr[1][0], b0,   c1, 0, 0, 0);
            c0 = MFMA16(fr[0][1], b1,   c0, 0, 0, 0);
            c1 = MFMA16(fr[1][1], b1,   c1, 0, 0, 0);
            c0 = MFMA16(fr[0][2], fb.v, c0, 0, 0, 0);
            c1 = MFMA16(fr[1][2], fb.v, c1, 0, 0, 0);

            unsigned short* hb = H1s + row*128;
            uint2 u;
            u.x = cvt_pk_bf16(fmaxf(c0[0], 0.f), fmaxf(c0[1], 0.f));
            u.y = cvt_pk_bf16(fmaxf(c0[2], 0.f), fmaxf(c0[3], 0.f));
            *(uint2*)(hb + (((w*4 + g2) ^ lw) << 3) + gh*4) = u;
            u.x = cvt_pk_bf16(fmaxf(c1[0], 0.f), fmaxf(c1[1], 0.f));
            u.y = cvt_pk_bf16(fmaxf(c1[2], 0.f), fmaxf(c1[3], 0.f));
            *(uint2*)(hb + (((w*4 + 2 + g2) ^ lw) << 3) + gh*4) = u;
        }
        __syncthreads();   // H1s written

        // ---- GEMM2: D2 = W2^T·H1^T ; masked colsum of relu(D2 + b2) ----
        #pragma unroll
        for (int pt = 0; pt < 8; pt++) {
            const int row = pt*16 + ln;
            const unsigned short* hbase = H1s + row*128;
            f32x4 d0 = {0.f,0.f,0.f,0.f}, d1 = {0.f,0.f,0.f,0.f};
            #pragma unroll
            for (int kk = 0; kk < 4; kk++) {
                s16x8 bf = *(const s16x8*)(hbase + (((kk*4 + g) ^ lw) << 3));
                d0 = MFMA16(fr[0][3+kk], bf, d0, 0, 0, 0);
                d1 = MFMA16(fr[1][3+kk], bf, d1, 0, 0, 0);
            }
            if (pos0 + row < lim) {
                #pragma unroll
                for (int i = 0; i < 4; i++) {
                    s[0][i] += fmaxf(d0[i] + bb2[0][i], 0.f);
                    s[1][i] += fmaxf(d1[i] + bb2[1][i], 0.f);
                }
            }
        }
        __syncthreads();   // H1s reads done (buffer reused next iter)
    }

    // reduce over the 16 lanes sharing each hidden index; one float4 store per (wave, mt)
    #pragma unroll
    for (int mt = 0; mt < 2; mt++)
        #pragma unroll
        for (int i = 0; i < 4; i++) {
            float v = s[mt][i];
            v += __shfl_xor(v, 1, 64); v += __shfl_xor(v, 2, 64);
            v += __shfl_xor(v, 4, 64); v += __shfl_xor(v, 8, 64);
            s[mt][i] = v;
        }
    if (ln == 0) {
        float* dst = wsp + (((size_t)(b*2 + mode)*8 + bx) << 7) + w*32;
        *(f32x4*)(dst +  0 + g*4) = f32x4{s[0][0], s[0][1], s[0][2], s[0][3]};
        *(f32x4*)(dst + 16 + g*4) = f32x4{s[1][0], s[1][1], s[1][2], s[1][3]};
    }
}

__global__ void ss_finish(const float* __restrict__ wsp,
                          const float* __restrict__ tpW3, const float* __restrict__ tpb3,
                          const float* __restrict__ ppW3, const float* __restrict__ ppb3,
                          float* __restrict__ out) {
    const int b = blockIdx.x, t = threadIdx.x;   // 128 threads
    const float* p0 = wsp + (size_t)(b*2 + 0) * 8 * 128;
    const float* p1 = wsp + (size_t)(b*2 + 1) * 8 * 128;
    float a0 = 0.f, a1 = 0.f;
    #pragma unroll
    for (int k = 0; k < 8; k++) {
        a0 += p0[k*128 + t];
        a1 += p1[k*128 + t];
    }
    float v = a0 * tpW3[t] + a1 * ppW3[t];
    #pragma unroll
    for (int off = 1; off < 64; off <<= 1) v += __shfl_xor(v, off, 64);
    __shared__ float ps[2];
    if ((t & 63) == 0) ps[t >> 6] = v;
    __syncthreads();
    if (t == 0) out[b] = ps[0] + ps[1] + 4093.f * tpb3[0] + 4092.f * ppb3[0];
}

extern "C" void kernel_launch(void* const* d_in, const int* in_sizes, int n_in,
                              void* d_out, int out_size, void* d_ws, size_t ws_size,
                              hipStream_t stream) {
    (void)in_sizes; (void)n_in; (void)out_size; (void)ws_size;
    const float* R    = (const float*)d_in[0];
    const int*   seq  = (const int*)d_in[1];
    const float* emb  = (const float*)d_in[2];
    const float* tpW1 = (const float*)d_in[3];
    const float* tpb1 = (const float*)d_in[4];
    const float* tpW2 = (const float*)d_in[5];
    const float* tpb2 = (const float*)d_in[6];
    const float* tpW3 = (const float*)d_in[7];
    const float* tpb3 = (const float*)d_in[8];
    const float* ppW1 = (const float*)d_in[9];
    const float* ppb1 = (const float*)d_in[10];
    const float* ppW2 = (const float*)d_in[11];
    const float* ppb2 = (const float*)d_in[12];
    const float* ppW3 = (const float*)d_in[13];
    const float* ppb3 = (const float*)d_in[14];

    char* wsb = (char*)d_ws;
    float* wsp   = (float*)wsb;                          // [0, 512KB): block partial sums
    uint2* featG = (uint2*)(wsb + (512<<10));            // [512KB, 512KB+2MB): features
    uint4* embbfG = (uint4*)(wsb + (512<<10) + (2<<20)); // 640 B (padded to 1 KB)
    uint4* wfragG = (uint4*)(wsb + (512<<10) + (2<<20) + 1024);  // 112 KB packed frags

    ss_pre<<<dim3(17, 64), 256, 0, stream>>>(R, featG, emb, embbfG,
                                             tpW1, tpb1, tpW2, ppW1, ppb1, ppW2, wfragG);
    ss_mlp<<<dim3(8, 64, 2), 256, 0, stream>>>(seq, featG, embbfG, wfragG,
                                               tpb2, ppb2, wsp);
    ss_finish<<<64, 128, 0, stream>>>(wsp, tpW3, tpb3, ppW3, ppb3, (float*)d_out);
}

// Round 11
// 56.876 us; speedup vs baseline: 1.3292x; 1.3292x over previous
//
#include <hip/hip_runtime.h>

#define L_   4096
#define LIM0 4093   // L-3 (tp positions)
#define LIM1 4092   // L-4 (pp positions)

typedef short s16x8 __attribute__((ext_vector_type(8)));
typedef float f32x4 __attribute__((ext_vector_type(4)));

__device__ __forceinline__ unsigned int cvt_pk_bf16(float lo, float hi) {
    unsigned int r;
    asm("v_cvt_pk_bf16_f32 %0, %1, %2" : "=v"(r) : "v"(lo), "v"(hi));
    return r;
}

struct F3 { float x, y, z; };
__device__ __forceinline__ F3 ld3(const float* p) { return F3{p[0], p[1], p[2]}; }
__device__ __forceinline__ F3 sub3(F3 a, F3 b) { return F3{a.x-b.x, a.y-b.y, a.z-b.z}; }
__device__ __forceinline__ F3 cross3(F3 a, F3 b) {
    return F3{a.y*b.z - a.z*b.y, a.z*b.x - a.x*b.z, a.x*b.y - a.y*b.x};
}
__device__ __forceinline__ float dot3(F3 a, F3 b) { return a.x*b.x + a.y*b.y + a.z*b.z; }

__device__ __forceinline__ void torsion(F3 a, F3 b, F3 c, F3 d, float& sn, float& cs) {
    F3 v1 = sub3(b, a), v2 = sub3(c, b), v3 = sub3(d, c);
    F3 n1 = cross3(v1, v2), n2 = cross3(v2, v3);
    float x = dot3(n1, n2);
    F3 m = cross3(n1, n2);
    float bn = sqrtf(dot3(v2, v2)) + 1e-8f;
    float y = dot3(m, v2) / bn;
    float inv = rsqrtf(x*x + y*y + 1e-30f);
    sn = y * inv; cs = x * inv;
}

#define MFMA16 __builtin_amdgcn_mfma_f32_16x16x32_bf16

// ---- pre-kernel: features (bx<16) + weight-frag packing over 28 blocks (bx==16) ----
__global__ __launch_bounds__(256) void ss_pre(
    const float* __restrict__ R, uint2* __restrict__ featG,
    const float* __restrict__ emb, uint4* __restrict__ embbfG,
    const float* __restrict__ tpW1, const float* __restrict__ tpb1,
    const float* __restrict__ tpW2,
    const float* __restrict__ ppW1, const float* __restrict__ ppb1,
    const float* __restrict__ ppW2,
    uint4* __restrict__ wfragG) {
    const int t = threadIdx.x;
    if (blockIdx.x == 16) {
        if (blockIdx.y >= 28) return;          // 28 blocks x 256 threads = 7168 fragments
        if (blockIdx.y == 0 && t < 40) {
            const float* ep = emb + (t >> 1) * 16 + (t & 1) * 8;
            embbfG[t] = make_uint4(cvt_pk_bf16(ep[0], ep[1]), cvt_pk_bf16(ep[2], ep[3]),
                                   cvt_pk_bf16(ep[4], ep[5]), cvt_pk_bf16(ep[6], ep[7]));
        }
        const int F = blockIdx.y * 256 + t;
        int l = F & 63, q = F >> 6;
        int kkL = q % 7; q /= 7;
        int mt = q & 1; q >>= 1;
        int w = q & 3, mode = q >> 2;
        int g = l >> 4, ln = l & 15;
        int hc = w*32 + mt*16 + ln;
        const float* W1  = mode ? ppW1 : tpW1;
        const float* Bi1 = mode ? ppb1 : tpb1;
        const float* W2  = mode ? ppW2 : tpW2;
        float v[8];
        #pragma unroll
        for (int j = 0; j < 8; j++) {
            if (kkL < 3) {
                int c = kkL*32 + g*8 + j;
                int kp;
                if (mode) kp = (c < 64) ? c + 4 : ((c < 68) ? c - 64 : ((c == 68) ? -2 : -1));
                else      kp = (c < 64) ? c + 3 : ((c == 64) ? 0 : ((c == 65) ? -2 :
                               ((c == 66) ? 1 : ((c == 67) ? 2 : -1))));
                v[j] = (kp == -1) ? 0.f : ((kp == -2) ? Bi1[hc] : W1[kp*128 + hc]);
            } else {
                v[j] = W2[((kkL - 3)*32 + g*8 + j)*128 + hc];
            }
        }
        wfragG[F] = make_uint4(cvt_pk_bf16(v[0], v[1]), cvt_pk_bf16(v[2], v[3]),
                               cvt_pk_bf16(v[4], v[5]), cvt_pk_bf16(v[6], v[7]));
        return;
    }
    const int p = blockIdx.x * 256 + t;
    const int b = blockIdx.y;
    if (p >= LIM0) return;
    const float* Rp = R + ((size_t)(b * L_ + p)) * 3;
    F3 p0 = ld3(Rp), p1 = ld3(Rp + 3), p2 = ld3(Rp + 6), p3 = ld3(Rp + 9);
    F3 u1 = sub3(p0, p1), u2 = sub3(p2, p1);
    F3 cr = cross3(u1, u2);
    float d = dot3(u1, u2);
    float ct = d * rsqrtf(d * d + dot3(cr, cr) + 1e-30f);
    float sp, cp; torsion(p0, p1, p2, p3, sp, cp);
    featG[(size_t)b * L_ + p] = make_uint2(cvt_pk_bf16(ct, 1.0f), cvt_pk_bf16(sp, cp));
}

// ---- main: M=128 tile, H1-only LDS with FULL 4-bit XOR swizzle; VMEM emb gathers ----
__global__ __launch_bounds__(256) void ss_mlp(
    const int* __restrict__ seq, const uint2* __restrict__ featG,
    const uint4* __restrict__ embbfG, const uint4* __restrict__ wfragG,
    const float* __restrict__ tpb2, const float* __restrict__ ppb2,
    float* __restrict__ wsp) {

    __shared__ __align__(16) unsigned short H1s[128*128];  // [pos][hidden], blk ^ (row&15)

    const int b = blockIdx.y, mode = blockIdx.z, bx = blockIdx.x;
    const int lim = mode ? LIM1 : LIM0;
    const float* Bi2 = mode ? ppb2 : tpb2;

    const int t = threadIdx.x;
    const int w = t >> 6, l = t & 63, g = l >> 4, ln = l & 15;
    const int g2 = g >> 1, gh = g & 1;
    const size_t bL = (size_t)b * L_;
    const int base = bx * 512;

    // prologue: 14 coalesced fragment loads + bias2
    s16x8 fr[2][7];
    {
        const uint4* wf = wfragG + (size_t)(mode*4 + w) * (2*7*64);
        #pragma unroll
        for (int mt = 0; mt < 2; mt++)
            #pragma unroll
            for (int kkL = 0; kkL < 7; kkL++)
                fr[mt][kkL] = *(const s16x8*)(wf + (mt*7 + kkL)*64 + l);
    }
    float bb2[2][4];
    #pragma unroll
    for (int mt = 0; mt < 2; mt++)
        #pragma unroll
        for (int i = 0; i < 4; i++)
            bb2[mt][i] = Bi2[w*32 + mt*16 + g*4 + i];

    float s[2][4] = {{0.f,0.f,0.f,0.f},{0.f,0.f,0.f,0.f}};

    for (int it = 0; it < 4; it++) {
        const int pos0 = base + it*128;

        // residue indices for all 8 sub-tiles (L1/L2-hot)
        int aa[8][2];
        #pragma unroll
        for (int pt = 0; pt < 8; pt++)
            #pragma unroll
            for (int e = 0; e < 2; e++)
                aa[pt][e] = seq[bL + min(pos0 + pt*16 + ln + e*2 + g2, L_ - 1)];

        // ---- GEMM1: D1 = W1^T·X^T, B-frags gathered from embbfG (VMEM) + featG ----
        #pragma unroll
        for (int pt = 0; pt < 8; pt++) {
            const int row = pt*16 + ln;
            const int pos = pos0 + row;
            s16x8 b0 = *(const s16x8*)(embbfG + aa[pt][0]*2 + gh);
            s16x8 b1 = *(const s16x8*)(embbfG + aa[pt][1]*2 + gh);
            uint2 f0 = make_uint2(0u, 0u), f1 = make_uint2(0u, 0u);
            if (g == 0) {
                const int pc = min(pos, lim - 1);
                f0 = featG[bL + pc];
                if (mode) f1 = featG[bL + pc + 1];
            }
            union { unsigned int u[4]; s16x8 v; } fb;
            if (mode) {
                fb.u[0] = f0.y; fb.u[1] = f1.y;
                fb.u[2] = (g == 0) ? 0x00003F80u : 0u; fb.u[3] = 0u;
            } else {
                fb.u[0] = f0.x; fb.u[1] = f0.y; fb.u[2] = 0u; fb.u[3] = 0u;
            }
            f32x4 c0 = {0.f,0.f,0.f,0.f}, c1 = {0.f,0.f,0.f,0.f};
            c0 = MFMA16(fr[0][0], b0,   c0, 0, 0, 0);
            c1 = MFMA16(fr[1][0], b0,   c1, 0, 0, 0);
            c0 = MFMA16(fr[0][1], b1,   c0, 0, 0, 0);
            c1 = MFMA16(fr[1][1], b1,   c1, 0, 0, 0);
            c0 = MFMA16(fr[0][2], fb.v, c0, 0, 0, 0);
            c1 = MFMA16(fr[1][2], fb.v, c1, 0, 0, 0);

            unsigned short* hb = H1s + row*128;
            uint2 u;
            u.x = cvt_pk_bf16(fmaxf(c0[0], 0.f), fmaxf(c0[1], 0.f));
            u.y = cvt_pk_bf16(fmaxf(c0[2], 0.f), fmaxf(c0[3], 0.f));
            *(uint2*)(hb + (((w*4 + g2) ^ ln) << 3) + gh*4) = u;
            u.x = cvt_pk_bf16(fmaxf(c1[0], 0.f), fmaxf(c1[1], 0.f));
            u.y = cvt_pk_bf16(fmaxf(c1[2], 0.f), fmaxf(c1[3], 0.f));
            *(uint2*)(hb + (((w*4 + 2 + g2) ^ ln) << 3) + gh*4) = u;
        }
        __syncthreads();   // H1s written

        // ---- GEMM2: D2 = W2^T·H1^T ; masked colsum of relu(D2 + b2) ----
        #pragma unroll
        for (int pt = 0; pt < 8; pt++) {
            const int row = pt*16 + ln;
            const unsigned short* hbase = H1s + row*128;
            f32x4 d0 = {0.f,0.f,0.f,0.f}, d1 = {0.f,0.f,0.f,0.f};
            #pragma unroll
            for (int kk = 0; kk < 4; kk++) {
                s16x8 bf = *(const s16x8*)(hbase + (((kk*4 + g) ^ ln) << 3));
                d0 = MFMA16(fr[0][3+kk], bf, d0, 0, 0, 0);
                d1 = MFMA16(fr[1][3+kk], bf, d1, 0, 0, 0);
            }
            if (pos0 + row < lim) {
                #pragma unroll
                for (int i = 0; i < 4; i++) {
                    s[0][i] += fmaxf(d0[i] + bb2[0][i], 0.f);
                    s[1][i] += fmaxf(d1[i] + bb2[1][i], 0.f);
                }
            }
        }
        __syncthreads();   // H1s reads done (buffer reused next iter)
    }

    // reduce over the 16 lanes sharing each hidden index; one float4 store per (wave, mt)
    #pragma unroll
    for (int mt = 0; mt < 2; mt++)
        #pragma unroll
        for (int i = 0; i < 4; i++) {
            float v = s[mt][i];
            v += __shfl_xor(v, 1, 64); v += __shfl_xor(v, 2, 64);
            v += __shfl_xor(v, 4, 64); v += __shfl_xor(v, 8, 64);
            s[mt][i] = v;
        }
    if (ln == 0) {
        float* dst = wsp + (((size_t)(b*2 + mode)*8 + bx) << 7) + w*32;
        *(f32x4*)(dst +  0 + g*4) = f32x4{s[0][0], s[0][1], s[0][2], s[0][3]};
        *(f32x4*)(dst + 16 + g*4) = f32x4{s[1][0], s[1][1], s[1][2], s[1][3]};
    }
}

__global__ void ss_finish(const float* __restrict__ wsp,
                          const float* __restrict__ tpW3, const float* __restrict__ tpb3,
                          const float* __restrict__ ppW3, const float* __restrict__ ppb3,
                          float* __restrict__ out) {
    const int b = blockIdx.x, t = threadIdx.x;   // 128 threads
    const float* p0 = wsp + (size_t)(b*2 + 0) * 8 * 128;
    const float* p1 = wsp + (size_t)(b*2 + 1) * 8 * 128;
    float a0 = 0.f, a1 = 0.f;
    #pragma unroll
    for (int k = 0; k < 8; k++) {
        a0 += p0[k*128 + t];
        a1 += p1[k*128 + t];
    }
    float v = a0 * tpW3[t] + a1 * ppW3[t];
    #pragma unroll
    for (int off = 1; off < 64; off <<= 1) v += __shfl_xor(v, off, 64);
    __shared__ float ps[2];
    if ((t & 63) == 0) ps[t >> 6] = v;
    __syncthreads();
    if (t == 0) out[b] = ps[0] + ps[1] + 4093.f * tpb3[0] + 4092.f * ppb3[0];
}

extern "C" void kernel_launch(void* const* d_in, const int* in_sizes, int n_in,
                              void* d_out, int out_size, void* d_ws, size_t ws_size,
                              hipStream_t stream) {
    (void)in_sizes; (void)n_in; (void)out_size; (void)ws_size;
    const float* R    = (const float*)d_in[0];
    const int*   seq  = (const int*)d_in[1];
    const float* emb  = (const float*)d_in[2];
    const float* tpW1 = (const float*)d_in[3];
    const float* tpb1 = (const float*)d_in[4];
    const float* tpW2 = (const float*)d_in[5];
    const float* tpb2 = (const float*)d_in[6];
    const float* tpW3 = (const float*)d_in[7];
    const float* tpb3 = (const float*)d_in[8];
    const float* ppW1 = (const float*)d_in[9];
    const float* ppb1 = (const float*)d_in[10];
    const float* ppW2 = (const float*)d_in[11];
    const float* ppb2 = (const float*)d_in[12];
    const float* ppW3 = (const float*)d_in[13];
    const float* ppb3 = (const float*)d_in[14];

    char* wsb = (char*)d_ws;
    float* wsp   = (float*)wsb;                          // [0, 512KB): block partial sums
    uint2* featG = (uint2*)(wsb + (512<<10));            // [512KB, 512KB+2MB): features
    uint4* embbfG = (uint4*)(wsb + (512<<10) + (2<<20)); // 640 B (padded to 1 KB)
    uint4* wfragG = (uint4*)(wsb + (512<<10) + (2<<20) + 1024);  // 112 KB packed frags

    ss_pre<<<dim3(17, 64), 256, 0, stream>>>(R, featG, emb, embbfG,
                                             tpW1, tpb1, tpW2, ppW1, ppb1, ppW2, wfragG);
    ss_mlp<<<dim3(8, 64, 2), 256, 0, stream>>>(seq, featG, embbfG, wfragG,
                                               tpb2, ppb2, wsp);
    ss_finish<<<64, 128, 0, stream>>>(wsp, tpW3, tpb3, ppW3, ppb3, (float*)d_out);
}